// Round 2
// baseline (332.502 us; speedup 1.0000x reference)
//
#include <hip/hip_runtime.h>

// Problem constants: B=64, T=512, D=1024, L=32
#define N_ROWS 32768          // B*T
#define OUT_LOSS_IDX 1048576  // B*T*L

typedef __attribute__((ext_vector_type(4))) float f32x4;
typedef __attribute__((ext_vector_type(4))) int i32x4;
typedef __attribute__((ext_vector_type(8))) short bf16x8;

__device__ __forceinline__ unsigned short f32_to_bf16(float f) {
    unsigned u = __float_as_uint(f);
    unsigned r = (u + 0x7FFFu + ((u >> 16) & 1u)) >> 16;
    return (unsigned short)r;
}
__device__ __forceinline__ float bf16_to_f32(unsigned short h) {
    return __uint_as_float(((unsigned)h) << 16);
}

// ---------------------------------------------------------------------------
// K0: W (1024x32 f32) -> Wt (32x1024 bf16) in workspace
// ---------------------------------------------------------------------------
__global__ void k0_wt(const float* __restrict__ W, unsigned short* __restrict__ Wt) {
    int idx = blockIdx.x * 256 + threadIdx.x;   // 0..32767, coalesced read
    int k = idx >> 5, c = idx & 31;
    Wt[c * 1024 + k] = f32_to_bf16(W[idx]);
}

// ---------------------------------------------------------------------------
// K1: logits = x*W + b (bf16 MFMA), fused softmax -> probs, logits(f32) -> ws
// Block: 256 thr (4 waves), 64 rows/block, K chunked by 128. Grid 512.
// ---------------------------------------------------------------------------
__global__ __launch_bounds__(256, 2) void k1_gemm(
    const float* __restrict__ x, const unsigned short* __restrict__ Wt,
    const float* __restrict__ bias, float* __restrict__ logits,
    float* __restrict__ probs) {
    __shared__ unsigned short xs[64 * 136];  // [row][k], pad 136 (=128+8) vs bank conflicts
    __shared__ unsigned short wls[32 * 136]; // [n][k] = W^T chunk

    const int tid = threadIdx.x;
    const int r0 = blockIdx.x * 64;
    const int lane = tid & 63, wave = tid >> 6;
    const int m = lane & 15, quad = lane >> 4;

    f32x4 acc0 = {0.f, 0.f, 0.f, 0.f};
    f32x4 acc1 = {0.f, 0.f, 0.f, 0.f};

    for (int ch = 0; ch < 8; ++ch) {
        const int k0 = ch * 128;
        // stage x chunk: 64 rows x 128 k (f32 -> bf16)
        #pragma unroll
        for (int l = 0; l < 8; ++l) {
            int idx = l * 256 + tid;           // 0..2047 float4 slots
            int row = idx >> 5, kq = idx & 31; // 32 float4 per row
            f32x4 v = *(const f32x4*)&x[(size_t)(r0 + row) * 1024 + k0 + kq * 4];
            ushort4 pv;
            pv.x = f32_to_bf16(v[0]); pv.y = f32_to_bf16(v[1]);
            pv.z = f32_to_bf16(v[2]); pv.w = f32_to_bf16(v[3]);
            *(ushort4*)&xs[row * 136 + kq * 4] = pv;
        }
        // stage W^T chunk: 32 n x 128 k bf16 (already converted)
        #pragma unroll
        for (int l = 0; l < 2; ++l) {
            int idx = l * 256 + tid;            // 0..511 16B slots
            int c = idx >> 4, part = idx & 15;
            *(f32x4*)&wls[c * 136 + part * 8] =
                *(const f32x4*)&Wt[c * 1024 + k0 + part * 8];
        }
        __syncthreads();
        #pragma unroll
        for (int ks = 0; ks < 4; ++ks) {
            bf16x8 a  = *(const bf16x8*)&xs[(wave * 16 + m) * 136 + ks * 32 + quad * 8];
            bf16x8 b0 = *(const bf16x8*)&wls[m * 136 + ks * 32 + quad * 8];
            bf16x8 b1 = *(const bf16x8*)&wls[(16 + m) * 136 + ks * 32 + quad * 8];
            acc0 = __builtin_amdgcn_mfma_f32_16x16x32_bf16(a, b0, acc0, 0, 0, 0);
            acc1 = __builtin_amdgcn_mfma_f32_16x16x32_bf16(a, b1, acc1, 0, 0, 0);
        }
        __syncthreads();
    }
    // epilogue: bias, write logits f32, fused row softmax -> probs
    const float bc0 = bias[m], bc1 = bias[16 + m];
    #pragma unroll
    for (int r = 0; r < 4; ++r) {
        int row = r0 + wave * 16 + quad * 4 + r;  // C/D: col=lane&15, row=quad*4+reg
        float l0 = acc0[r] + bc0;
        float l1 = acc1[r] + bc1;
        logits[row * 32 + m] = l0;
        logits[row * 32 + 16 + m] = l1;
        float mx = fmaxf(l0, l1);
        #pragma unroll
        for (int d = 1; d < 16; d <<= 1) mx = fmaxf(mx, __shfl_xor(mx, d, 64));
        float e0 = __expf(l0 - mx), e1 = __expf(l1 - mx);
        float s = e0 + e1;
        #pragma unroll
        for (int d = 1; d < 16; d <<= 1) s += __shfl_xor(s, d, 64);
        float inv = 1.0f / s;
        probs[row * 32 + m] = e0 * inv;
        probs[row * 32 + 16 + m] = e1 * inv;
    }
}

// ---------------------------------------------------------------------------
// K3: CRF forward (logZ per batch). One wave per batch (64 blocks x 64 thr).
// Lane j(=lane&31) owns state j; halves split the i-sum (16 each).
// Mask is int32 (harness promotes bool -> int).
// ---------------------------------------------------------------------------
__global__ __launch_bounds__(64, 1) void k3_crf(
    const float* __restrict__ logits, const int* __restrict__ mask,
    const float* __restrict__ trans, const float* __restrict__ start_t,
    const float* __restrict__ end_t, float* __restrict__ logZ) {
    __shared__ unsigned short slog[512 * 32];  // logits staged bf16 (32 KB)
    __shared__ int smask[512];                 // 2 KB

    const int b = blockIdx.x, lane = threadIdx.x;
    const int j = lane & 31, h = lane >> 5;

    const float* gl = logits + (size_t)b * 16384;
    #pragma unroll 8
    for (int it = 0; it < 64; ++it) {
        int idx = it * 64 + lane;  // float4 index 0..4095
        f32x4 v = *(const f32x4*)&gl[idx * 4];
        ushort4 pv;
        pv.x = f32_to_bf16(v[0]); pv.y = f32_to_bf16(v[1]);
        pv.z = f32_to_bf16(v[2]); pv.w = f32_to_bf16(v[3]);
        *(ushort4*)&slog[idx * 4] = pv;
    }
    #pragma unroll
    for (int it = 0; it < 2; ++it) {
        int idx = it * 64 + lane;  // int4 index 0..127
        *(i32x4*)&smask[idx * 4] = *(const i32x4*)&mask[b * 512 + idx * 4];
    }
    __syncthreads();

    float tcE[16];  // exp(trans[i][j]) for i = h*16 + ii
    #pragma unroll
    for (int ii = 0; ii < 16; ++ii)
        tcE[ii] = __expf(trans[(h * 16 + ii) * 32 + j]);

    float alpha = start_t[j] + bf16_to_f32(slog[j]);  // t = 0

    for (int t = 1; t < 512; ++t) {
        float lt = bf16_to_f32(slog[t * 32 + j]);
        int mk = smask[t];
        float c = __shfl(alpha, 0, 64);
        float v = __expf(alpha - c);
        float s0 = 0.f, s1 = 0.f, s2 = 0.f, s3 = 0.f;
        #pragma unroll
        for (int ii = 0; ii < 16; ii += 4) {
            s0 += __shfl(v, h * 16 + ii + 0, 64) * tcE[ii + 0];
            s1 += __shfl(v, h * 16 + ii + 1, 64) * tcE[ii + 1];
            s2 += __shfl(v, h * 16 + ii + 2, 64) * tcE[ii + 2];
            s3 += __shfl(v, h * 16 + ii + 3, 64) * tcE[ii + 3];
        }
        float s = (s0 + s1) + (s2 + s3);
        s += __shfl_xor(s, 32, 64);  // combine i-halves
        float na = c + __logf(s) + lt;
        alpha = mk ? na : alpha;
    }
    float f = alpha + end_t[j];
    float mx = f;
    #pragma unroll
    for (int d = 1; d < 32; d <<= 1) mx = fmaxf(mx, __shfl_xor(mx, d, 64));
    float e = __expf(f - mx), s = e;
    #pragma unroll
    for (int d = 1; d < 32; d <<= 1) s += __shfl_xor(s, d, 64);
    if (lane == 0) logZ[b] = mx + __logf(s);
}

// ---------------------------------------------------------------------------
// K4: gold (joint) score per batch. 64 blocks x 256 threads. Mask is int32.
// ---------------------------------------------------------------------------
__global__ __launch_bounds__(256) void k4_gold(
    const float* __restrict__ logits, const int* __restrict__ mask,
    const int* __restrict__ labels, const float* __restrict__ trans,
    const float* __restrict__ start_t, const float* __restrict__ end_t,
    float* __restrict__ gold) {
    const int b = blockIdx.x, tid = threadIdx.x;
    const int base = b * 512;
    float partial = 0.f;
    int cnt = 0;
    #pragma unroll
    for (int l = 0; l < 2; ++l) {
        int tt = l * 256 + tid;
        int mk = mask[base + tt];
        float mf = mk ? 1.f : 0.f;
        cnt += mk ? 1 : 0;
        int tag = labels[base + tt];
        if (tt >= 1) {
            int prev = labels[base + tt - 1];
            partial += trans[prev * 32 + tag] * mf;
        }
        if (tt <= 510) partial += logits[(size_t)(base + tt) * 32 + tag] * mf;
    }
    #pragma unroll
    for (int d = 1; d < 64; d <<= 1) {
        partial += __shfl_xor(partial, d, 64);
        cnt += __shfl_xor(cnt, d, 64);
    }
    __shared__ float sp[4];
    __shared__ int sc[4];
    int wave = tid >> 6;
    if ((tid & 63) == 0) { sp[wave] = partial; sc[wave] = cnt; }
    __syncthreads();
    if (tid == 0) {
        float tot = sp[0] + sp[1] + sp[2] + sp[3];
        int len = sc[0] + sc[1] + sc[2] + sc[3];
        int first = labels[base];
        int last = labels[base + len - 1];
        float g = tot + start_t[first] + end_t[last];
        g += logits[(size_t)(base + 511) * 32 + last] * (mask[base + 511] ? 1.f : 0.f);
        gold[b] = g;
    }
}

// ---------------------------------------------------------------------------
// K5: loss = sum_b (logZ[b] - gold[b]) -> d_out[B*T*L]
// ---------------------------------------------------------------------------
__global__ void k5_loss(const float* __restrict__ logZ, const float* __restrict__ gold,
                        float* __restrict__ out) {
    int lane = threadIdx.x;
    float v = logZ[lane] - gold[lane];
    #pragma unroll
    for (int d = 1; d < 64; d <<= 1) v += __shfl_xor(v, d, 64);
    if (lane == 0) out[OUT_LOSS_IDX] = v;
}

extern "C" void kernel_launch(void* const* d_in, const int* in_sizes, int n_in,
                              void* d_out, int out_size, void* d_ws, size_t ws_size,
                              hipStream_t stream) {
    const float* x       = (const float*)d_in[0];
    const int* mk        = (const int*)d_in[1];   // bool mask promoted to int32
    const int* labels    = (const int*)d_in[2];
    const float* W       = (const float*)d_in[3];
    const float* bias    = (const float*)d_in[4];
    const float* trans   = (const float*)d_in[5];
    const float* start_t = (const float*)d_in[6];
    const float* end_t   = (const float*)d_in[7];

    float* probs = (float*)d_out;
    float* ws = (float*)d_ws;
    float* logits = ws;                                        // 1048576 f32 (4 MB)
    unsigned short* Wt = (unsigned short*)(ws + 1048576);      // 32768 bf16 (64 KB)
    float* logZ = ws + 1048576 + 16384;                        // 64 f32
    float* gold = logZ + 64;                                   // 64 f32

    k0_wt<<<128, 256, 0, stream>>>(W, Wt);
    k1_gemm<<<512, 256, 0, stream>>>(x, Wt, bias, logits, probs);
    k3_crf<<<64, 64, 0, stream>>>(logits, mk, trans, start_t, end_t, logZ);
    k4_gold<<<64, 256, 0, stream>>>(logits, mk, labels, trans, start_t, end_t, gold);
    k5_loss<<<1, 64, 0, stream>>>(logZ, gold, probs);
}

// Round 3
// 303.675 us; speedup vs baseline: 1.0949x; 1.0949x over previous
//
#include <hip/hip_runtime.h>

// Problem constants: B=64, T=512, D=1024, L=32
#define OUT_LOSS_IDX 1048576  // B*T*L

typedef __attribute__((ext_vector_type(4))) float f32x4;
typedef __attribute__((ext_vector_type(4))) int i32x4;
typedef __attribute__((ext_vector_type(8))) short bf16x8;

__device__ __forceinline__ unsigned short f32_to_bf16(float f) {
    unsigned u = __float_as_uint(f);
    unsigned r = (u + 0x7FFFu + ((u >> 16) & 1u)) >> 16;
    return (unsigned short)r;
}

// ---------------------------------------------------------------------------
// K0: W (1024x32 f32) -> Wt (32x1024 bf16) in workspace
// ---------------------------------------------------------------------------
__global__ void k0_wt(const float* __restrict__ W, unsigned short* __restrict__ Wt) {
    int idx = blockIdx.x * 256 + threadIdx.x;   // 0..32767, coalesced read
    int k = idx >> 5, c = idx & 31;
    Wt[c * 1024 + k] = f32_to_bf16(W[idx]);
}

// ---------------------------------------------------------------------------
// K1: logits = x*W + b (bf16 MFMA) + fused softmax. No LDS: A-frags straight
// from global (deep MLP), B-frags from global (64 KB -> L2-resident).
// 1 wave / 16 rows. Grid 2048 x 64.
// ---------------------------------------------------------------------------
__global__ __launch_bounds__(64) void k1_gemm(
    const float* __restrict__ x, const unsigned short* __restrict__ Wt,
    const float* __restrict__ bias, float* __restrict__ logits,
    float* __restrict__ probs) {
    const int lane = threadIdx.x;
    const int m = lane & 15, quad = lane >> 4;
    const int r0 = blockIdx.x * 16;

    const float* xa = x + (size_t)(r0 + m) * 1024 + quad * 8;
    const unsigned short* wb0 = Wt + (size_t)m * 1024 + quad * 8;
    const unsigned short* wb1 = Wt + (size_t)(m + 16) * 1024 + quad * 8;

    f32x4 acc0 = {0.f, 0.f, 0.f, 0.f};
    f32x4 acc1 = {0.f, 0.f, 0.f, 0.f};

    #pragma unroll 4
    for (int ks = 0; ks < 32; ++ks) {
        f32x4 a0 = *(const f32x4*)(xa + ks * 32);
        f32x4 a1 = *(const f32x4*)(xa + ks * 32 + 4);
        bf16x8 b0 = *(const bf16x8*)(wb0 + ks * 32);
        bf16x8 b1 = *(const bf16x8*)(wb1 + ks * 32);
        bf16x8 af;
        af[0] = (short)f32_to_bf16(a0[0]); af[1] = (short)f32_to_bf16(a0[1]);
        af[2] = (short)f32_to_bf16(a0[2]); af[3] = (short)f32_to_bf16(a0[3]);
        af[4] = (short)f32_to_bf16(a1[0]); af[5] = (short)f32_to_bf16(a1[1]);
        af[6] = (short)f32_to_bf16(a1[2]); af[7] = (short)f32_to_bf16(a1[3]);
        acc0 = __builtin_amdgcn_mfma_f32_16x16x32_bf16(af, b0, acc0, 0, 0, 0);
        acc1 = __builtin_amdgcn_mfma_f32_16x16x32_bf16(af, b1, acc1, 0, 0, 0);
    }
    // epilogue: bias, logits f32, fused row softmax -> probs
    const float bc0 = bias[m], bc1 = bias[16 + m];
    #pragma unroll
    for (int r = 0; r < 4; ++r) {
        int row = r0 + quad * 4 + r;  // C/D: col=lane&15, row=quad*4+reg
        float l0 = acc0[r] + bc0;
        float l1 = acc1[r] + bc1;
        logits[row * 32 + m] = l0;
        logits[row * 32 + 16 + m] = l1;
        float mx = fmaxf(l0, l1);
        #pragma unroll
        for (int d = 1; d < 16; d <<= 1) mx = fmaxf(mx, __shfl_xor(mx, d, 64));
        float e0 = __expf(l0 - mx), e1 = __expf(l1 - mx);
        float s = e0 + e1;
        #pragma unroll
        for (int d = 1; d < 16; d <<= 1) s += __shfl_xor(s, d, 64);
        float inv = 1.0f / s;
        probs[row * 32 + m] = e0 * inv;
        probs[row * 32 + 16 + m] = e1 * inv;
    }
}

// ---------------------------------------------------------------------------
// K3: CRF forward in EXP SPACE. p_j = exp(alpha_j - C); step:
//   p' = (sum_i p_i E_ij) * elt_j,  E = exp(trans) in regs,
//   elt = exp(logit) precomputed in LDS (f32) during staging.
// Rescale by p_0 every 4 steps (overflow-safe; log(c) accumulation off-chain).
// One wave per batch. Mask is int32.
// ---------------------------------------------------------------------------
__global__ __launch_bounds__(64, 1) void k3_crf(
    const float* __restrict__ logits, const int* __restrict__ mask,
    const float* __restrict__ trans, const float* __restrict__ start_t,
    const float* __restrict__ end_t, float* __restrict__ logZ) {
    __shared__ float sElt[512 * 32];  // exp(logits), 64 KB
    __shared__ int smask[512];        // 2 KB

    const int b = blockIdx.x, lane = threadIdx.x;
    const int j = lane & 31, h = lane >> 5;

    const float* gl = logits + (size_t)b * 16384;
    #pragma unroll 4
    for (int it = 0; it < 64; ++it) {
        int idx = it * 64 + lane;  // float4 index 0..4095
        f32x4 v = *(const f32x4*)&gl[idx * 4];
        f32x4 e = {__expf(v[0]), __expf(v[1]), __expf(v[2]), __expf(v[3])};
        *(f32x4*)&sElt[idx * 4] = e;
    }
    #pragma unroll
    for (int it = 0; it < 2; ++it) {
        int idx = it * 64 + lane;
        *(i32x4*)&smask[idx * 4] = *(const i32x4*)&mask[b * 512 + idx * 4];
    }
    __syncthreads();

    float tcE[16];  // exp(trans[i][j]) for i = h*16 + ii
    #pragma unroll
    for (int ii = 0; ii < 16; ++ii)
        tcE[ii] = __expf(trans[(h * 16 + ii) * 32 + j]);

    // t = 0: p_j = exp(start_j) * exp(l0_j), then normalize by p_0
    float p = __expf(start_t[j]) * sElt[j];
    float c0 = __shfl(p, 0, 64);
    p *= __builtin_amdgcn_rcpf(c0);
    float logC = __logf(c0);

    #pragma unroll 4
    for (int t = 1; t < 512; ++t) {
        float elt = sElt[t * 32 + j];
        int mk = smask[t];
        float s0 = 0.f, s1 = 0.f, s2 = 0.f, s3 = 0.f;
        #pragma unroll
        for (int ii = 0; ii < 16; ii += 4) {
            s0 = fmaf(__shfl(p, h * 16 + ii + 0, 64), tcE[ii + 0], s0);
            s1 = fmaf(__shfl(p, h * 16 + ii + 1, 64), tcE[ii + 1], s1);
            s2 = fmaf(__shfl(p, h * 16 + ii + 2, 64), tcE[ii + 2], s2);
            s3 = fmaf(__shfl(p, h * 16 + ii + 3, 64), tcE[ii + 3], s3);
        }
        float s = (s0 + s1) + (s2 + s3);
        s += __shfl_xor(s, 32, 64);  // combine i-halves
        float q = s * elt;
        p = mk ? q : p;
        if ((t & 3) == 3) {  // rescale: keeps p in f32 range
            float c = __shfl(p, 0, 64);
            p *= __builtin_amdgcn_rcpf(c);
            logC += __logf(c);
        }
    }
    // logZ = logC + logsumexp_j(log p_j + end_j)
    float f = logC + __logf(p) + end_t[j];
    float mx = f;
    #pragma unroll
    for (int d = 1; d < 32; d <<= 1) mx = fmaxf(mx, __shfl_xor(mx, d, 64));
    float e = __expf(f - mx), s = e;
    #pragma unroll
    for (int d = 1; d < 32; d <<= 1) s += __shfl_xor(s, d, 64);
    if (lane == 0) logZ[b] = mx + __logf(s);
}

// ---------------------------------------------------------------------------
// K4: gold (joint) score per batch. 64 blocks x 256 threads. Mask is int32.
// ---------------------------------------------------------------------------
__global__ __launch_bounds__(256) void k4_gold(
    const float* __restrict__ logits, const int* __restrict__ mask,
    const int* __restrict__ labels, const float* __restrict__ trans,
    const float* __restrict__ start_t, const float* __restrict__ end_t,
    float* __restrict__ gold) {
    const int b = blockIdx.x, tid = threadIdx.x;
    const int base = b * 512;
    float partial = 0.f;
    int cnt = 0;
    #pragma unroll
    for (int l = 0; l < 2; ++l) {
        int tt = l * 256 + tid;
        int mk = mask[base + tt];
        float mf = mk ? 1.f : 0.f;
        cnt += mk ? 1 : 0;
        int tag = labels[base + tt];
        if (tt >= 1) {
            int prev = labels[base + tt - 1];
            partial += trans[prev * 32 + tag] * mf;
        }
        if (tt <= 510) partial += logits[(size_t)(base + tt) * 32 + tag] * mf;
    }
    #pragma unroll
    for (int d = 1; d < 64; d <<= 1) {
        partial += __shfl_xor(partial, d, 64);
        cnt += __shfl_xor(cnt, d, 64);
    }
    __shared__ float sp[4];
    __shared__ int sc[4];
    int wave = tid >> 6;
    if ((tid & 63) == 0) { sp[wave] = partial; sc[wave] = cnt; }
    __syncthreads();
    if (tid == 0) {
        float tot = sp[0] + sp[1] + sp[2] + sp[3];
        int len = sc[0] + sc[1] + sc[2] + sc[3];
        int first = labels[base];
        int last = labels[base + len - 1];
        float g = tot + start_t[first] + end_t[last];
        g += logits[(size_t)(base + 511) * 32 + last] * (mask[base + 511] ? 1.f : 0.f);
        gold[b] = g;
    }
}

// ---------------------------------------------------------------------------
// K5: loss = sum_b (logZ[b] - gold[b]) -> d_out[B*T*L]
// ---------------------------------------------------------------------------
__global__ void k5_loss(const float* __restrict__ logZ, const float* __restrict__ gold,
                        float* __restrict__ out) {
    int lane = threadIdx.x;
    float v = logZ[lane] - gold[lane];
    #pragma unroll
    for (int d = 1; d < 64; d <<= 1) v += __shfl_xor(v, d, 64);
    if (lane == 0) out[OUT_LOSS_IDX] = v;
}

extern "C" void kernel_launch(void* const* d_in, const int* in_sizes, int n_in,
                              void* d_out, int out_size, void* d_ws, size_t ws_size,
                              hipStream_t stream) {
    const float* x       = (const float*)d_in[0];
    const int* mk        = (const int*)d_in[1];   // bool mask promoted to int32
    const int* labels    = (const int*)d_in[2];
    const float* W       = (const float*)d_in[3];
    const float* bias    = (const float*)d_in[4];
    const float* trans   = (const float*)d_in[5];
    const float* start_t = (const float*)d_in[6];
    const float* end_t   = (const float*)d_in[7];

    float* probs = (float*)d_out;
    float* ws = (float*)d_ws;
    float* logits = ws;                                        // 1048576 f32 (4 MB)
    unsigned short* Wt = (unsigned short*)(ws + 1048576);      // 32768 bf16 (64 KB)
    float* logZ = ws + 1048576 + 16384;                        // 64 f32
    float* gold = logZ + 64;                                   // 64 f32

    k0_wt<<<128, 256, 0, stream>>>(W, Wt);
    k1_gemm<<<2048, 64, 0, stream>>>(x, Wt, bias, logits, probs);
    k3_crf<<<64, 64, 0, stream>>>(logits, mk, trans, start_t, end_t, logZ);
    k4_gold<<<64, 256, 0, stream>>>(logits, mk, labels, trans, start_t, end_t, gold);
    k5_loss<<<1, 64, 0, stream>>>(logZ, gold, probs);
}